// Round 11
// baseline (399.603 us; speedup 1.0000x reference)
//
#include <hip/hip_runtime.h>
#include <hip/hip_fp16.h>
#include <cstddef>

// SS3D block: in_proj -> dwconv3d+silu -> {12-dir spatial selective scan + channel selective scan}
// -> layernorm -> *silu(z) -> out_proj.
// Dims: B=2, H=16, W=16, D=8, L=2048, D_MODEL=96, D_INNER=192, N=16, K=12, R=6,
//       D_PROJ=128, R_CH=8.
// NOTE: the reference's un-permute for directions 3 and 4 is NOT the inverse of the
// forward permutation (VMamba quirk) — output-side shift tables g_h* replicate it exactly.
// Spatial scan: chunked 2-pass parallel linear recurrence.
// History: R2 monolithic 12% occ; R4 scattered loads; R6 xdbl K-split; R8 2 states/lane;
// R9 NCHUNK16+sSO; R10 4 states/lane, NCHUNK32 -> sp2 80us @ 89% VALUBusy (issue-bound).
// R11: pre computes P=exp(A*sum(dt)) (kills 4 P-muls/step); du + sSO read in 2-step
// batches (sp2 DS/step 4->3); k_xdbl 8-way K-split (24-c chains, 1536 blocks).

#define NCHUNK 32
#define CLEN   64
#define TSTEP  32
#define NTILE  (CLEN / TSTEP)
#define SCAN_IDX_N 73728   // B*K*C*N = 2*12*192*16

__device__ __forceinline__ float siluf(float v) { return v / (1.0f + __expf(-v)); }
__device__ __forceinline__ float softplusf(float v) {
  return (v > 20.0f) ? v : log1pf(__expf(v));
}

// DPP cross-lane adds (VALU pipe, no LDS latency).
template <int CTRL>
__device__ __forceinline__ float dpp_mov(float v) {
  return __int_as_float(__builtin_amdgcn_update_dpp(0, __float_as_int(v), CTRL, 0xF, 0xF, true));
}
__device__ __forceinline__ float red4_dpp(float v) {  // sum within lane quad
  v += dpp_mov<0xB1>(v);    // quad_perm xor1
  v += dpp_mov<0x4E>(v);    // quad_perm xor2
  return v;
}
__device__ __forceinline__ float red8_dpp(float v) {  // sum over 8 consecutive lanes
  v += dpp_mov<0xB1>(v);
  v += dpp_mov<0x4E>(v);
  v += dpp_mov<0x141>(v);   // row_half_mirror
  return v;
}
__device__ __forceinline__ float red16_dpp(float v) {
  v += dpp_mov<0xB1>(v);
  v += dpp_mov<0x4E>(v);
  v += dpp_mov<0x141>(v);
  v += dpp_mov<0x140>(v);   // row_mirror
  return v;
}

// ---------------------------------------------------------------------------
// K1: in_proj GEMM.  out[i,j] = sum_k x[i,k]*W[j,k], i in [0,4096), j in [0,384).
__global__ __launch_bounds__(256) void k_inproj(const float* __restrict__ x,
    const float* __restrict__ W, float* __restrict__ xin_t, float* __restrict__ z) {
  __shared__ float As[64][17];
  __shared__ float Bs[64][17];
  int i0 = blockIdx.x * 64, j0 = blockIdx.y * 64;
  int tid = threadIdx.x, tx = tid & 15, ty = tid >> 4;
  int lrow = tid >> 2, lk4 = (tid & 3) << 2;
  float acc[4][4] = {};
  for (int k0 = 0; k0 < 96; k0 += 16) {
    float4 va = *(const float4*)(x + (size_t)(i0 + lrow) * 96 + k0 + lk4);
    float4 vb = *(const float4*)(W + (size_t)(j0 + lrow) * 96 + k0 + lk4);
    As[lrow][lk4+0] = va.x; As[lrow][lk4+1] = va.y; As[lrow][lk4+2] = va.z; As[lrow][lk4+3] = va.w;
    Bs[lrow][lk4+0] = vb.x; Bs[lrow][lk4+1] = vb.y; Bs[lrow][lk4+2] = vb.z; Bs[lrow][lk4+3] = vb.w;
    __syncthreads();
#pragma unroll
    for (int kk = 0; kk < 16; ++kk) {
      float a0 = As[ty*4+0][kk], a1 = As[ty*4+1][kk], a2 = As[ty*4+2][kk], a3 = As[ty*4+3][kk];
      float b0 = Bs[tx*4+0][kk], b1 = Bs[tx*4+1][kk], b2 = Bs[tx*4+2][kk], b3 = Bs[tx*4+3][kk];
      acc[0][0] = fmaf(a0,b0,acc[0][0]); acc[0][1] = fmaf(a0,b1,acc[0][1]);
      acc[0][2] = fmaf(a0,b2,acc[0][2]); acc[0][3] = fmaf(a0,b3,acc[0][3]);
      acc[1][0] = fmaf(a1,b0,acc[1][0]); acc[1][1] = fmaf(a1,b1,acc[1][1]);
      acc[1][2] = fmaf(a1,b2,acc[1][2]); acc[1][3] = fmaf(a1,b3,acc[1][3]);
      acc[2][0] = fmaf(a2,b0,acc[2][0]); acc[2][1] = fmaf(a2,b1,acc[2][1]);
      acc[2][2] = fmaf(a2,b2,acc[2][2]); acc[2][3] = fmaf(a2,b3,acc[2][3]);
      acc[3][0] = fmaf(a3,b0,acc[3][0]); acc[3][1] = fmaf(a3,b1,acc[3][1]);
      acc[3][2] = fmaf(a3,b2,acc[3][2]); acc[3][3] = fmaf(a3,b3,acc[3][3]);
    }
    __syncthreads();
  }
#pragma unroll
  for (int r = 0; r < 4; ++r) {
    int i = i0 + ty*4 + r; int b = i >> 11, l = i & 2047;
#pragma unroll
    for (int sc = 0; sc < 4; ++sc) {
      int j = j0 + tx*4 + sc;
      float v = acc[r][sc];
      if (j < 192) xin_t[((size_t)b*192 + j)*2048 + l] = v;
      else         z[((size_t)(b*2048 + l))*192 + (j - 192)] = siluf(v);
    }
  }
}

// ---------------------------------------------------------------------------
// K2: depthwise 3x3x3 conv (SAME, zero pad) + bias + silu.
__global__ __launch_bounds__(256) void k_conv(const float* __restrict__ xin_t,
    const float* __restrict__ cw, const float* __restrict__ cb, float* __restrict__ xc) {
  int idx = blockIdx.x * 256 + threadIdx.x;       // (b*192+c)*2048 + l
  int l = idx & 2047; int bc = idx >> 11; int c = bc % 192;
  int d = l & 7, w = (l >> 3) & 15, h = l >> 7;
  const float* xp = xin_t + (size_t)bc * 2048;
  const float* wp = cw + c * 27;
  float acc = cb[c];
#pragma unroll
  for (int kh = -1; kh <= 1; ++kh) {
    int hh = h + kh; if (hh < 0 || hh > 15) continue;
#pragma unroll
    for (int kw = -1; kw <= 1; ++kw) {
      int ww = w + kw; if (ww < 0 || ww > 15) continue;
#pragma unroll
      for (int kd = -1; kd <= 1; ++kd) {
        int dd = d + kd; if (dd < 0 || dd > 7) continue;
        acc = fmaf(xp[(hh*16 + ww)*8 + dd], wp[(kh+1)*9 + (kw+1)*3 + (kd+1)], acc);
      }
    }
  }
  xc[idx] = siluf(acc);
}

// Forward permutation decode: scan position l -> (i0,i1,i2); input spatial
// s_in = i0<<h0 | i1<<h1 | i2<<h2 (where u is read).
__device__ __constant__ int c_s2[6]  = {3,4,3,4,4,4};   // log2 dim(i2)
__device__ __constant__ int c_s1[6]  = {4,3,4,3,4,4};   // log2 dim(i1)
__device__ __constant__ int c_h0[6]  = {7,7,3,3,0,0};
__device__ __constant__ int c_h1[6]  = {3,0,7,0,7,3};
__device__ __constant__ int c_h2[6]  = {0,3,0,7,3,7};
// Output-side (reference's actual unperm; NOT the inverse for pk=3,4).
__device__ __constant__ int g_h0[6]  = {7,7,3,0,4,0};
__device__ __constant__ int g_h1[6]  = {3,0,7,8,0,3};
__device__ __constant__ int g_h2[6]  = {0,3,0,4,7,7};

// ---------------------------------------------------------------------------
// K3: per (b,k,l): x_dbl[38] = Wk(38x192) . xs_col(192).
// 8-lane group splits the 192-sum 8x (24 c's each), red8-DPP reduce.
// B/C interleaved [l][2n]=B_n,[2n+1]=C_n; raw dt-rank values (6) -> dts_raw[l][8].
__global__ __launch_bounds__(256) void k_xdbl(const float* __restrict__ xc,
    const float* __restrict__ xpw, float* __restrict__ xdblT, float* __restrict__ dts_raw) {
  int k = blockIdx.y, b = blockIdx.z;
  int tid = threadIdx.x;
  int l = blockIdx.x * 32 + (tid >> 3);
  int slice = tid & 7;
  __shared__ float sW[38*192];
  for (int i = tid; i < 38*192; i += 256) sW[i] = xpw[k*38*192 + i];
  __syncthreads();
  int pk = k % 6;
  int lr = (k < 6) ? l : (2047 - l);
  int s2 = c_s2[pk], s1 = c_s1[pk];
  int i2 = lr & ((1 << s2) - 1);
  int tt = lr >> s2;
  int i1 = tt & ((1 << s1) - 1);
  int i0 = tt >> s1;
  int s = (i0 << c_h0[pk]) | (i1 << c_h1[pk]) | (i2 << c_h2[pk]);
  float acc[38];
#pragma unroll
  for (int cc = 0; cc < 38; ++cc) acc[cc] = 0.0f;
  const float* up = xc + (size_t)b * 192 * 2048 + s;
  for (int ci = 0; ci < 24; ++ci) {
    int c = ci * 8 + slice;
    float u = up[(size_t)c * 2048];
#pragma unroll
    for (int cc = 0; cc < 38; ++cc) acc[cc] = fmaf(sW[cc*192 + c], u, acc[cc]);
  }
#pragma unroll
  for (int cc = 0; cc < 38; ++cc) acc[cc] = red8_dpp(acc[cc]);
  int bk = b * 12 + k;
  float4* xo4 = (float4*)(xdblT + ((size_t)bk * 2048 + l) * 32);
  int n = slice * 2;
  xo4[slice] = make_float4(acc[6+n], acc[22+n], acc[7+n], acc[23+n]);
  float* dr = dts_raw + ((size_t)bk * 2048 + l) * 8;
  if (slice < 3) *(float2*)(dr + slice*2) = make_float2(acc[slice*2], acc[slice*2+1]);
}

// ---------------------------------------------------------------------------
// LDS-tiled scan kernels (32-step tiles, register-prefetched staging).
// Block covers 64 c's for one (k, b, chunk j); lane = cs*4+q holds n in {4q..4q+3};
// wave covers 16 c's. dt recomputed from dts_raw in staging.

// K4 pass 1: chunk-local scan from h=0; P = exp(A*sum(dt)) (no per-step P-muls), h_end.
__global__ __launch_bounds__(256) void k_scan_pre(const float* __restrict__ xdblT,
    const float* __restrict__ dts_raw, const float* __restrict__ xc,
    const float* __restrict__ dtw, const float* __restrict__ dtb,
    const float* __restrict__ A_logs, float* __restrict__ Pbuf, float* __restrict__ hend) {
  __shared__ float sB[TSTEP*16];     // [li][n] B only
  __shared__ float sDU[64*(TSTEP*2+2)];  // [c_loc][li*2] {dt,u}, row stride 66
  __shared__ float sDTW[64*6];
  __shared__ float sDTB[64];
  int cg = blockIdx.x, k = blockIdx.y;
  int b = blockIdx.z >> 5, j = blockIdx.z & 31;
  int tid = threadIdx.x;
  int lane = tid & 63, wid = tid >> 6;
  int q = lane & 3, cs = lane >> 2;
  int n0 = q * 4;
  int c_loc = wid * 16 + cs;
  int c = cg * 64 + c_loc;
  int bk = b * 12 + k;
  for (int i = tid; i < 384; i += 256) sDTW[i] = dtw[k*1152 + cg*384 + i];
  if (tid < 64)  sDTB[tid] = dtb[k*192 + cg*64 + tid];
  float4 Al = *(const float4*)&A_logs[((size_t)(k*192 + c))*16 + n0];
  float A0 = -__expf(Al.x), A1 = -__expf(Al.y), A2 = -__expf(Al.z), A3 = -__expf(Al.w);
  int pk = k % 6;
  int s2 = c_s2[pk], s1 = c_s1[pk];
  int h0s = c_h0[pk], h1s = c_h1[pk], h2s = c_h2[pk];
  int m2 = (1 << s2) - 1, m1 = (1 << s1) - 1;
  bool rev = (k >= 6);
  int l0 = j * CLEN;
  int dl = tid & 31, cq = tid >> 5;            // DU staging: step dl, c-group cq (8 c's)
  const float4* bcg4 = (const float4*)(xdblT + (size_t)bk * 2048 * 32);
  const float*  drg  = dts_raw + ((size_t)bk * 2048) * 8;
  const float*  ug   = xc + ((size_t)b * 192 + cg * 64 + cq * 8) * 2048;
  // prefetch tile 0
  float4 pbc = bcg4[(l0 + (tid >> 3)) * 8 + (tid & 7)];
  float4 pr0 = *(const float4*)(drg + (size_t)(l0 + dl) * 8);
  float2 pr1 = *(const float2*)(drg + (size_t)(l0 + dl) * 8 + 4);
  float pu[8];
  {
    int l = l0 + dl;
    int lr = rev ? (2047 - l) : l;
    int i2 = lr & m2; int tt2 = lr >> s2; int i1 = tt2 & m1; int i0 = tt2 >> s1;
    int s_in = (i0 << h0s) | (i1 << h1s) | (i2 << h2s);
#pragma unroll
    for (int i = 0; i < 8; ++i) pu[i] = ug[s_in + (size_t)i * 2048];
  }
  float h0 = 0.f, h1 = 0.f, h2 = 0.f, h3 = 0.f;
  float sdt = 0.f;
  for (int t = 0; t < NTILE; ++t) {
    __syncthreads();
    {   // B-only tile: thread reads one BC float4 (covers n-pair), writes 2 B's
      int li = tid >> 3, jj = tid & 7;
      *(float2*)&sB[li*16 + jj*2] = make_float2(pbc.x, pbc.z);
    }
#pragma unroll
    for (int i = 0; i < 8; ++i) {
      int cc = cq * 8 + i;
      const float* wr = &sDTW[cc*6];
      float v = sDTB[cc];
      v = fmaf(pr0.x, wr[0], v); v = fmaf(pr0.y, wr[1], v); v = fmaf(pr0.z, wr[2], v);
      v = fmaf(pr0.w, wr[3], v); v = fmaf(pr1.x, wr[4], v); v = fmaf(pr1.y, wr[5], v);
      *(float2*)&sDU[cc*66 + dl*2] = make_float2(softplusf(v), pu[i]);
    }
    __syncthreads();
    if (t < NTILE - 1) {
      int lt = l0 + (t + 1) * TSTEP;
      pbc = bcg4[(lt + (tid >> 3)) * 8 + (tid & 7)];
      pr0 = *(const float4*)(drg + (size_t)(lt + dl) * 8);
      pr1 = *(const float2*)(drg + (size_t)(lt + dl) * 8 + 4);
      int l = lt + dl;
      int lr = rev ? (2047 - l) : l;
      int i2 = lr & m2; int tt2 = lr >> s2; int i1 = tt2 & m1; int i0 = tt2 >> s1;
      int s_in = (i0 << h0s) | (i1 << h1s) | (i2 << h2s);
#pragma unroll
      for (int i = 0; i < 8; ++i) pu[i] = ug[s_in + (size_t)i * 2048];
    }
#pragma unroll 4
    for (int li = 0; li < TSTEP; li += 2) {
      float4 du2 = *(const float4*)&sDU[c_loc*66 + li*2];   // dt0,u0,dt1,u1
      float4 b4a = *(const float4*)&sB[li*16 + n0];
      {
        float dtu = du2.x * du2.y;
        float dA0 = __expf(du2.x * A0);
        float dA1 = __expf(du2.x * A1);
        float dA2 = __expf(du2.x * A2);
        float dA3 = __expf(du2.x * A3);
        h0 = fmaf(h0, dA0, dtu * b4a.x);
        h1 = fmaf(h1, dA1, dtu * b4a.y);
        h2 = fmaf(h2, dA2, dtu * b4a.z);
        h3 = fmaf(h3, dA3, dtu * b4a.w);
      }
      float4 b4b = *(const float4*)&sB[(li+1)*16 + n0];
      {
        float dtu = du2.z * du2.w;
        float dA0 = __expf(du2.z * A0);
        float dA1 = __expf(du2.z * A1);
        float dA2 = __expf(du2.z * A2);
        float dA3 = __expf(du2.z * A3);
        h0 = fmaf(h0, dA0, dtu * b4b.x);
        h1 = fmaf(h1, dA1, dtu * b4b.y);
        h2 = fmaf(h2, dA2, dtu * b4b.z);
        h3 = fmaf(h3, dA3, dtu * b4b.w);
      }
      sdt += du2.x + du2.z;
    }
  }
  size_t idx = ((size_t)bk * 192 + c) * 16 + n0;
  float P0 = __expf(A0 * sdt), P1 = __expf(A1 * sdt);
  float P2 = __expf(A2 * sdt), P3 = __expf(A3 * sdt);
  *(float4*)&Pbuf[(size_t)j * SCAN_IDX_N + idx] = make_float4(P0, P1, P2, P3);
  *(float4*)&hend[(size_t)j * SCAN_IDX_N + idx] = make_float4(h0, h1, h2, h3);
}

// K4 carry: serial combine over 32 chunks -> H_init per chunk (in-place over Pbuf).
__global__ __launch_bounds__(256) void k_scan_carry(float* __restrict__ Pbuf,
    const float* __restrict__ hend) {
  int idx = blockIdx.x * 256 + threadIdx.x;    // 73728
  float S = 0.0f;
#pragma unroll
  for (int j = 0; j < NCHUNK; ++j) {
    float p = Pbuf[(size_t)j * SCAN_IDX_N + idx];
    float e = hend[(size_t)j * SCAN_IDX_N + idx];
    Pbuf[(size_t)j * SCAN_IDX_N + idx] = S;     // H_init for chunk j
    S = fmaf(S, p, e);
  }
}

// K4 pass 2: re-scan each chunk from H_init; 4-lane DPP reduce; atomic un-permute.
__global__ __launch_bounds__(256) void k_scan_sp2(const float* __restrict__ xdblT,
    const float* __restrict__ dts_raw, const float* __restrict__ xc,
    const float* __restrict__ dtw, const float* __restrict__ dtb,
    const float* __restrict__ A_logs, const float* __restrict__ Dsv,
    const float* __restrict__ Hinit, float* __restrict__ y_acc) {
  __shared__ float sBC[TSTEP*32];    // [li][2n]=B,[2n+1]=C
  __shared__ float sDU[64*(TSTEP*2+2)];
  __shared__ float sDTW[64*6];
  __shared__ float sDTB[64];
  __shared__ int   sSO[TSTEP];       // s_out*192 per li
  int cg = blockIdx.x, k = blockIdx.y;
  int b = blockIdx.z >> 5, j = blockIdx.z & 31;
  int tid = threadIdx.x;
  int lane = tid & 63, wid = tid >> 6;
  int q = lane & 3, cs = lane >> 2;
  int n0 = q * 4;
  int c_loc = wid * 16 + cs;
  int c = cg * 64 + c_loc;
  int bk = b * 12 + k;
  int ch = k * 192 + c;
  for (int i = tid; i < 384; i += 256) sDTW[i] = dtw[k*1152 + cg*384 + i];
  if (tid < 64)  sDTB[tid] = dtb[k*192 + cg*64 + tid];
  float4 Al = *(const float4*)&A_logs[(size_t)ch*16 + n0];
  float A0 = -__expf(Al.x), A1 = -__expf(Al.y), A2 = -__expf(Al.z), A3 = -__expf(Al.w);
  float Dv = Dsv[ch];
  float* ybase = y_acc + (size_t)b * 2048 * 192 + c;
  int pk = k % 6;
  int s2 = c_s2[pk], s1 = c_s1[pk];
  int h0s = c_h0[pk], h1s = c_h1[pk], h2s = c_h2[pk];
  int e0 = g_h0[pk], e1 = g_h1[pk], e2 = g_h2[pk];
  int m2 = (1 << s2) - 1, m1 = (1 << s1) - 1;
  bool rev = (k >= 6);
  int l0 = j * CLEN;
  int dl = tid & 31, cq = tid >> 5;
  const float4* bcg4 = (const float4*)(xdblT + (size_t)bk * 2048 * 32);
  const float*  drg  = dts_raw + ((size_t)bk * 2048) * 8;
  const float*  ug   = xc + ((size_t)b * 192 + cg * 64 + cq * 8) * 2048;
  float4 pbc = bcg4[(l0 + (tid >> 3)) * 8 + (tid & 7)];
  float4 pr0 = *(const float4*)(drg + (size_t)(l0 + dl) * 8);
  float2 pr1 = *(const float2*)(drg + (size_t)(l0 + dl) * 8 + 4);
  float pu[8];
  {
    int l = l0 + dl;
    int lr = rev ? (2047 - l) : l;
    int i2 = lr & m2; int tt2 = lr >> s2; int i1 = tt2 & m1; int i0 = tt2 >> s1;
    int s_in = (i0 << h0s) | (i1 << h1s) | (i2 << h2s);
#pragma unroll
    for (int i = 0; i < 8; ++i) pu[i] = ug[s_in + (size_t)i * 2048];
  }
  float4 hi = *(const float4*)&Hinit[(size_t)j * SCAN_IDX_N + ((size_t)bk * 192 + c) * 16 + n0];
  float h0 = hi.x, h1 = hi.y, h2 = hi.z, h3 = hi.w;
  for (int t = 0; t < NTILE; ++t) {
    __syncthreads();
    ((float4*)sBC)[tid] = pbc;
#pragma unroll
    for (int i = 0; i < 8; ++i) {
      int cc = cq * 8 + i;
      const float* wr = &sDTW[cc*6];
      float v = sDTB[cc];
      v = fmaf(pr0.x, wr[0], v); v = fmaf(pr0.y, wr[1], v); v = fmaf(pr0.z, wr[2], v);
      v = fmaf(pr0.w, wr[3], v); v = fmaf(pr1.x, wr[4], v); v = fmaf(pr1.y, wr[5], v);
      *(float2*)&sDU[cc*66 + dl*2] = make_float2(softplusf(v), pu[i]);
    }
    if (tid < TSTEP) {                        // s_out*192 broadcast table
      int l = l0 + t*TSTEP + tid;
      int lr = rev ? (2047 - l) : l;
      int i2 = lr & m2; int tt2 = lr >> s2; int i1 = tt2 & m1; int i0 = tt2 >> s1;
      sSO[tid] = ((i0 << e0) | (i1 << e1) | (i2 << e2)) * 192;
    }
    __syncthreads();
    if (t < NTILE - 1) {
      int lt = l0 + (t + 1) * TSTEP;
      pbc = bcg4[(lt + (tid >> 3)) * 8 + (tid & 7)];
      pr0 = *(const float4*)(drg + (size_t)(lt + dl) * 8);
      pr1 = *(const float2*)(drg + (size_t)(lt + dl) * 8 + 4);
      int l = lt + dl;
      int lr = rev ? (2047 - l) : l;
      int i2 = lr & m2; int tt2 = lr >> s2; int i1 = tt2 & m1; int i0 = tt2 >> s1;
      int s_in = (i0 << h0s) | (i1 << h1s) | (i2 << h2s);
#pragma unroll
      for (int i = 0; i < 8; ++i) pu[i] = ug[s_in + (size_t)i * 2048];
    }
#pragma unroll 4
    for (int li = 0; li < TSTEP; li += 2) {
      float4 du2 = *(const float4*)&sDU[c_loc*66 + li*2];   // dt0,u0,dt1,u1
      int2 so2 = *(const int2*)&sSO[li];
      {
        float4 bc0 = ((const float4*)sBC)[li*8 + q*2];
        float4 bc1 = ((const float4*)sBC)[li*8 + q*2 + 1];
        float dtu = du2.x * du2.y;
        float dA0 = __expf(du2.x * A0);
        float dA1 = __expf(du2.x * A1);
        float dA2 = __expf(du2.x * A2);
        float dA3 = __expf(du2.x * A3);
        h0 = fmaf(h0, dA0, dtu * bc0.x);
        h1 = fmaf(h1, dA1, dtu * bc0.z);
        h2 = fmaf(h2, dA2, dtu * bc1.x);
        h3 = fmaf(h3, dA3, dtu * bc1.z);
        float yv = h0 * bc0.y;
        yv = fmaf(h1, bc0.w, yv);
        yv = fmaf(h2, bc1.y, yv);
        yv = fmaf(h3, bc1.w, yv);
        yv = red4_dpp(yv);
        if (q == 0) atomicAdd(ybase + so2.x, yv + Dv * du2.y);
      }
      {
        float4 bc0 = ((const float4*)sBC)[(li+1)*8 + q*2];
        float4 bc1 = ((const float4*)sBC)[(li+1)*8 + q*2 + 1];
        float dtu = du2.z * du2.w;
        float dA0 = __expf(du2.z * A0);
        float dA1 = __expf(du2.z * A1);
        float dA2 = __expf(du2.z * A2);
        float dA3 = __expf(du2.z * A3);
        h0 = fmaf(h0, dA0, dtu * bc0.x);
        h1 = fmaf(h1, dA1, dtu * bc0.z);
        h2 = fmaf(h2, dA2, dtu * bc1.x);
        h3 = fmaf(h3, dA3, dtu * bc1.z);
        float yv = h0 * bc0.y;
        yv = fmaf(h1, bc0.w, yv);
        yv = fmaf(h2, bc1.y, yv);
        yv = fmaf(h3, bc1.w, yv);
        yv = red4_dpp(yv);
        if (q == 0) atomicAdd(ybase + so2.y, yv + Dv * du2.w);
      }
    }
  }
}

// ---------------------------------------------------------------------------
// K5a: xd[b][p][c] = sum_l xc[b][c][l]*down_w[p][l] (+down_b[p]), K-split with atomics.
__global__ __launch_bounds__(256) void k_down(const float* __restrict__ dw,
    const float* __restrict__ db, const float* __restrict__ xc, float* __restrict__ xd) {
  __shared__ float As[64][17];
  __shared__ float Bs[64][17];
  int ks = blockIdx.x;                       // 16 K slices of 128
  int py = blockIdx.y / 3, cy = blockIdx.y % 3;
  int b = blockIdx.z;
  int p0 = py * 64, c0 = cy * 64;
  int tid = threadIdx.x, tx = tid & 15, ty = tid >> 4;
  int lrow = tid >> 2, lk4 = (tid & 3) << 2;
  float acc[4][4] = {};
  int kbase = ks * 128;
  for (int k0 = kbase; k0 < kbase + 128; k0 += 16) {
    float4 va = *(const float4*)(dw + (size_t)(p0 + lrow) * 2048 + k0 + lk4);
    float4 vb = *(const float4*)(xc + ((size_t)b*192 + c0 + lrow) * 2048 + k0 + lk4);
    As[lrow][lk4+0] = va.x; As[lrow][lk4+1] = va.y; As[lrow][lk4+2] = va.z; As[lrow][lk4+3] = va.w;
    Bs[lrow][lk4+0] = vb.x; Bs[lrow][lk4+1] = vb.y; Bs[lrow][lk4+2] = vb.z; Bs[lrow][lk4+3] = vb.w;
    __syncthreads();
#pragma unroll
    for (int kk = 0; kk < 16; ++kk) {
      float a0 = As[ty*4+0][kk], a1 = As[ty*4+1][kk], a2 = As[ty*4+2][kk], a3 = As[ty*4+3][kk];
      float b0 = Bs[tx*4+0][kk], b1 = Bs[tx*4+1][kk], b2 = Bs[tx*4+2][kk], b3 = Bs[tx*4+3][kk];
      acc[0][0] = fmaf(a0,b0,acc[0][0]); acc[0][1] = fmaf(a0,b1,acc[0][1]);
      acc[0][2] = fmaf(a0,b2,acc[0][2]); acc[0][3] = fmaf(a0,b3,acc[0][3]);
      acc[1][0] = fmaf(a1,b0,acc[1][0]); acc[1][1] = fmaf(a1,b1,acc[1][1]);
      acc[1][2] = fmaf(a1,b2,acc[1][2]); acc[1][3] = fmaf(a1,b3,acc[1][3]);
      acc[2][0] = fmaf(a2,b0,acc[2][0]); acc[2][1] = fmaf(a2,b1,acc[2][1]);
      acc[2][2] = fmaf(a2,b2,acc[2][2]); acc[2][3] = fmaf(a2,b3,acc[2][3]);
      acc[3][0] = fmaf(a3,b0,acc[3][0]); acc[3][1] = fmaf(a3,b1,acc[3][1]);
      acc[3][2] = fmaf(a3,b2,acc[3][2]); acc[3][3] = fmaf(a3,b3,acc[3][3]);
    }
    __syncthreads();
  }
#pragma unroll
  for (int r = 0; r < 4; ++r) {
    int p = p0 + ty*4 + r;
    float bias = (ks == 0) ? db[p] : 0.0f;
#pragma unroll
    for (int sc = 0; sc < 4; ++sc) {
      int c = c0 + tx*4 + sc;
      atomicAdd(&xd[((size_t)b*128 + p)*192 + c], acc[r][sc] + bias);
    }
  }
}

// K5b1: xdbl_c[b][n][c] = sum_p xd[b][p][c] * xpc_w[n][p]  (4 indep accumulators for MLP)
__global__ __launch_bounds__(256) void k_xdblc(const float* __restrict__ xd,
    const float* __restrict__ xpcw, float* __restrict__ xdblc) {
  int idx = blockIdx.x * 256 + threadIdx.x;   // 2*40*192 = 15360
  int c = idx % 192; int n = (idx / 192) % 40; int b = idx / (192 * 40);
  const float* xb = xd + (size_t)b*128*192 + c;
  const float* wb = xpcw + n*128;
  float a0 = 0.f, a1 = 0.f, a2 = 0.f, a3 = 0.f;
#pragma unroll 4
  for (int p = 0; p < 128; p += 4) {
    a0 = fmaf(xb[(size_t)(p+0)*192], wb[p+0], a0);
    a1 = fmaf(xb[(size_t)(p+1)*192], wb[p+1], a1);
    a2 = fmaf(xb[(size_t)(p+2)*192], wb[p+2], a2);
    a3 = fmaf(xb[(size_t)(p+3)*192], wb[p+3], a3);
  }
  xdblc[((size_t)b*40 + n)*192 + c] = (a0 + a1) + (a2 + a3);
}

// K5b2: dt_c[b][p][c] = softplus(sum_r xdbl_c[b][r][c]*dtc_w[p][r] + dtc_b[p])
__global__ __launch_bounds__(256) void k_dtc(const float* __restrict__ xdblc,
    const float* __restrict__ dtcw, const float* __restrict__ dtcb, float* __restrict__ dt_c) {
  int idx = blockIdx.x * 256 + threadIdx.x;   // 2*128*192 = 49152
  int c = idx % 192; int p = (idx / 192) % 128; int b = idx / (192 * 128);
  float acc = dtcb[p];
#pragma unroll
  for (int r = 0; r < 8; ++r)
    acc = fmaf(xdblc[((size_t)b*40 + r)*192 + c], dtcw[p*8 + r], acc);
  dt_c[idx] = softplusf(acc);
}

// K5c: channel selective scan over 192 steps; lane per (p,n); float4 batch prefetch (MLP).
__global__ __launch_bounds__(256) void k_scan_ch(const float* __restrict__ xdblc,
    const float* __restrict__ dt_c, const float* __restrict__ xd,
    const float* __restrict__ Alc, const float* __restrict__ Dsc, float* __restrict__ y_ch) {
  int pg = blockIdx.x, b = blockIdx.y;
  int lane = threadIdx.x & 63, wid = threadIdx.x >> 6;
  int p = pg * 16 + wid * 4 + (lane >> 4);
  int n = lane & 15;
  float A = -__expf(Alc[p * 16 + n]);
  float Dv = Dsc[p];
  const float* Brow = xdblc + ((size_t)b*40 + 8 + n) * 192;
  const float* Crow = Brow + (size_t)16 * 192;
  const float* dtrow = dt_c + ((size_t)b*128 + p) * 192;
  const float* urow = xd + ((size_t)b*128 + p) * 192;
  float* yrow = y_ch + ((size_t)b*128 + p) * 192;
  float h = 0.0f;
  float4 d4 = *(const float4*)dtrow;
  float4 u4 = *(const float4*)urow;
  float4 B4 = *(const float4*)Brow;
  float4 C4 = *(const float4*)Crow;
  for (int ct0 = 0; ct0 < 192; ct0 += 4) {
    float4 nd, nu, nB, nC;
    if (ct0 < 188) {
      nd = *(const float4*)(dtrow + ct0 + 4);
      nu = *(const float4*)(urow + ct0 + 4);
      nB = *(const float4*)(Brow + ct0 + 4);
      nC = *(const float4*)(Crow + ct0 + 4);
    }
    float dts[4] = {d4.x, d4.y, d4.z, d4.w};
    float us[4]  = {u4.x, u4.y, u4.z, u4.w};
    float Bs_[4] = {B4.x, B4.y, B4.z, B4.w};
    float Cs_[4] = {C4.x, C4.y, C4.z, C4.w};
#pragma unroll
    for (int s = 0; s < 4; ++s) {
      float dA = __expf(dts[s] * A);
      h = fmaf(h, dA, dts[s] * us[s] * Bs_[s]);
      float yv = red16_dpp(h * Cs_[s]);
      if (n == 0) yrow[ct0 + s] = yv + Dv * us[s];
    }
    d4 = nd; u4 = nu; B4 = nB; C4 = nC;
  }
}

// K5d: y_acc[b][l][c] += sum_p y_ch[b][p][c]*up_w[l][p] + up_b[l]
__global__ __launch_bounds__(256) void k_up(const float* __restrict__ uw,
    const float* __restrict__ ub, const float* __restrict__ ych, float* __restrict__ y_acc) {
  __shared__ float As[64][17];
  __shared__ float Bs[64][17];
  int l0 = blockIdx.x * 64, c0 = blockIdx.y * 64, b = blockIdx.z;
  int tid = threadIdx.x, tx = tid & 15, ty = tid >> 4;
  int lrow = tid >> 2, lk4 = (tid & 3) << 2;
  int bc4 = (tid & 15) << 2, bpp = tid >> 4;    // B-tile loader: 4 consecutive c at fixed p
  float acc[4][4] = {};
  for (int k0 = 0; k0 < 128; k0 += 16) {
    float4 va = *(const float4*)(uw + (size_t)(l0 + lrow) * 128 + k0 + lk4);
    float4 vb = *(const float4*)(ych + ((size_t)b*128 + k0 + bpp) * 192 + c0 + bc4);
    As[lrow][lk4+0] = va.x; As[lrow][lk4+1] = va.y; As[lrow][lk4+2] = va.z; As[lrow][lk4+3] = va.w;
    Bs[bc4+0][bpp] = vb.x; Bs[bc4+1][bpp] = vb.y; Bs[bc4+2][bpp] = vb.z; Bs[bc4+3][bpp] = vb.w;
    __syncthreads();
#pragma unroll
    for (int kk = 0; kk < 16; ++kk) {
      float a0 = As[ty*4+0][kk], a1 = As[ty*4+1][kk], a2 = As[ty*4+2][kk], a3 = As[ty*4+3][kk];
      float b0 = Bs[tx*4+0][kk], b1 = Bs[tx*4+1][kk], b2 = Bs[tx*4+2][kk], b3 = Bs[tx*4+3][kk];
      acc[0][0] = fmaf(a0,b0,acc[0][0]); acc[0][1] = fmaf(a0,b1,acc[0][1]);
      acc[0][2] = fmaf(a0,b2,acc[0][2]); acc[0][3] = fmaf(a0,b3,acc[0][3]);
      acc[1][0] = fmaf(a1,b0,acc[1][0]); acc[1][1] = fmaf(a1,b1,acc[1][1]);
      acc[1][2] = fmaf(a1,b2,acc[1][2]); acc[1][3] = fmaf(a1,b3,acc[1][3]);
      acc[2][0] = fmaf(a2,b0,acc[2][0]); acc[2][1] = fmaf(a2,b1,acc[2][1]);
      acc[2][2] = fmaf(a2,b2,acc[2][2]); acc[2][3] = fmaf(a2,b3,acc[2][3]);
      acc[3][0] = fmaf(a3,b0,acc[3][0]); acc[3][1] = fmaf(a3,b1,acc[3][1]);
      acc[3][2] = fmaf(a3,b2,acc[3][2]); acc[3][3] = fmaf(a3,b3,acc[3][3]);
    }
    __syncthreads();
  }
#pragma unroll
  for (int r = 0; r < 4; ++r) {
    int l = l0 + ty*4 + r;
    float ubl = ub[l];
#pragma unroll
    for (int sc = 0; sc < 4; ++sc) {
      int c = c0 + tx*4 + sc;
      size_t idx = ((size_t)b*2048 + l) * 192 + c;
      y_acc[idx] += acc[r][sc] + ubl;
    }
  }
}

// K6a: layernorm over C=192 + gate by silu(z); one wave per position.
__global__ __launch_bounds__(256) void k_lngate(const float* __restrict__ y_acc,
    const float* __restrict__ z, const float* __restrict__ nw, const float* __restrict__ nb,
    float* __restrict__ t) {
  int wpos = blockIdx.x * 4 + (threadIdx.x >> 6);
  int lane = threadIdx.x & 63;
  const float* yr = y_acc + (size_t)wpos * 192;
  float x0 = yr[lane], x1 = yr[lane + 64], x2 = yr[lane + 128];
  float s = x0 + x1 + x2;
  float q = x0*x0 + x1*x1 + x2*x2;
  for (int m = 32; m; m >>= 1) { s += __shfl_xor(s, m, 64); q += __shfl_xor(q, m, 64); }
  float mu = s * (1.0f / 192.0f);
  float var = q * (1.0f / 192.0f) - mu * mu;
  float rstd = rsqrtf(var + 1e-5f);
  const float* zr = z + (size_t)wpos * 192;
  float* tr = t + (size_t)wpos * 192;
  tr[lane]       = ((x0 - mu) * rstd * nw[lane]       + nb[lane])       * zr[lane];
  tr[lane + 64]  = ((x1 - mu) * rstd * nw[lane + 64]  + nb[lane + 64])  * zr[lane + 64];
  tr[lane + 128] = ((x2 - mu) * rstd * nw[lane + 128] + nb[lane + 128]) * zr[lane + 128];
}

// K6b: out[i][o] = sum_c t[i][c]*Wop[o][c], o<96 (N tile padded to 64x2).
__global__ __launch_bounds__(256) void k_outproj(const float* __restrict__ t,
    const float* __restrict__ W, float* __restrict__ out) {
  __shared__ float As[64][17];
  __shared__ float Bs[64][17];
  int i0 = blockIdx.x * 64, j0 = blockIdx.y * 64;
  int tid = threadIdx.x, tx = tid & 15, ty = tid >> 4;
  int lrow = tid >> 2, lk4 = (tid & 3) << 2;
  float acc[4][4] = {};
  for (int k0 = 0; k0 < 192; k0 += 16) {
    float4 va = *(const float4*)(t + (size_t)(i0 + lrow) * 192 + k0 + lk4);
    int wr = j0 + lrow;
    float4 vb = (wr < 96) ? *(const float4*)(W + (size_t)wr * 192 + k0 + lk4)
                          : make_float4(0.f, 0.f, 0.f, 0.f);
    As[lrow][lk4+0] = va.x; As[lrow][lk4+1] = va.y; As[lrow][lk4+2] = va.z; As[lrow][lk4+3] = va.w;
    Bs[lrow][lk4+0] = vb.x; Bs[lrow][lk4+1] = vb.y; Bs[lrow][lk4+2] = vb.z; Bs[lrow][lk4+3] = vb.w;
    __syncthreads();
#pragma unroll
    for (int kk = 0; kk < 16; ++kk) {
      float a0 = As[ty*4+0][kk], a1 = As[ty*4+1][kk], a2 = As[ty*4+2][kk], a3 = As[ty*4+3][kk];
      float b0 = Bs[tx*4+0][kk], b1 = Bs[tx*4+1][kk], b2 = Bs[tx*4+2][kk], b3 = Bs[tx*4+3][kk];
      acc[0][0] = fmaf(a0,b0,acc[0][0]); acc[0][1] = fmaf(a0,b1,acc[0][1]);
      acc[0][2] = fmaf(a0,b2,acc[0][2]); acc[0][3] = fmaf(a0,b3,acc[0][3]);
      acc[1][0] = fmaf(a1,b0,acc[1][0]); acc[1][1] = fmaf(a1,b1,acc[1][1]);
      acc[1][2] = fmaf(a1,b2,acc[1][2]); acc[1][3] = fmaf(a1,b3,acc[1][3]);
      acc[2][0] = fmaf(a2,b0,acc[2][0]); acc[2][1] = fmaf(a2,b1,acc[2][1]);
      acc[2][2] = fmaf(a2,b2,acc[2][2]); acc[2][3] = fmaf(a2,b3,acc[2][3]);
      acc[3][0] = fmaf(a3,b0,acc[3][0]); acc[3][1] = fmaf(a3,b1,acc[3][1]);
      acc[3][2] = fmaf(a3,b2,acc[3][2]); acc[3][3] = fmaf(a3,b3,acc[3][3]);
    }
    __syncthreads();
  }
#pragma unroll
  for (int r = 0; r < 4; ++r) {
    int i = i0 + ty*4 + r;
#pragma unroll
    for (int sc = 0; sc < 4; ++sc) {
      int j = j0 + tx*4 + sc;
      if (j < 96) out[(size_t)i * 96 + j] = acc[r][sc];
    }
  }
}

// ---------------------------------------------------------------------------
extern "C" void kernel_launch(void* const* d_in, const int* in_sizes, int n_in,
                              void* d_out, int out_size, void* d_ws, size_t ws_size,
                              hipStream_t stream) {
  (void)in_sizes; (void)n_in; (void)out_size; (void)ws_size;
  const float* x    = (const float*)d_in[0];
  const float* ipw  = (const float*)d_in[1];
  const float* cw   = (const float*)d_in[2];
  const float* cb   = (const float*)d_in[3];
  const float* xpw  = (const float*)d_in[4];
  const float* dtw  = (const float*)d_in[5];
  const float* dtb  = (const float*)d_in[6];
  const float* Alog = (const float*)d_in[7];
  const float* Dsp  = (const float*)d_in[8];
  const float* xpcw = (const float*)d_in[9];
  const float* dtcw = (const float*)d_in[10];
  const float* dtcb = (const float*)d_in[11];
  const float* Alc  = (const float*)d_in[12];
  const float* Dsc  = (const float*)d_in[13];
  const float* dwn  = (const float*)d_in[14];
  const float* dwb  = (const float*)d_in[15];
  const float* upw  = (const float*)d_in[16];
  const float* upb  = (const float*)d_in[17];
  const float* nw   = (const float*)d_in[18];
  const float* nb   = (const float*)d_in[19];
  const float* opw  = (const float*)d_in[20];
  float* out = (float*)d_out;

  float* ws = (float*)d_ws;
  float* xin_t  = ws;                         // 786432  (B,192,L); dead after conv
  float* zbuf   = xin_t + 786432;             // 786432  (B,L,192) silu'd
  float* xcbuf  = zbuf + 786432;              // 786432  (B,192,L)
  float* xdblT  = xcbuf + 786432;             // 1572864 (B,12,L,32) interleaved B/C
  float* dts_r  = xdblT + 1572864;            // 393216  (B,12,L,8) raw dt-rank values
  float* y_acc  = dts_r + 393216;             // 786432  (B,L,192)  [zeroed]
  float* xd     = y_acc + 786432;             // 49152   (B,128,192) [zeroed, atomics]
  float* xdbl_c = xd + 49152;                 // 15360   (B,40,192)
  float* dt_c   = xdbl_c + 15360;             // 49152   (B,128,192)
  float* y_ch   = dt_c + 49152;               // 49152   (B,128,192)
  float* Pbuf   = y_ch + 49152;               // NCHUNK*73728 = 2359296
  float* hendb  = Pbuf + 2359296;             // 2359296; dead after carry
  float* tbuf   = hendb;                      // overlaps hend (written by lngate, after scans)
                                              // total ~40.0 MB

  k_inproj<<<dim3(64, 6), 256, 0, stream>>>(x, ipw, xin_t, zbuf);
  k_conv<<<3072, 256, 0, stream>>>(xin_t, cw, cb, xcbuf);
  k_xdbl<<<dim3(64, 12, 2), 256, 0, stream>>>(xcbuf, xpw, xdblT, dts_r);
  hipMemsetAsync(y_acc, 0, (size_t)(786432 + 49152) * sizeof(float), stream);
  k_scan_pre<<<dim3(3, 12, 64), 256, 0, stream>>>(xdblT, dts_r, xcbuf, dtw, dtb, Alog, Pbuf, hendb);
  k_scan_carry<<<288, 256, 0, stream>>>(Pbuf, hendb);
  k_scan_sp2<<<dim3(3, 12, 64), 256, 0, stream>>>(xdblT, dts_r, xcbuf, dtw, dtb, Alog, Dsp, Pbuf, y_acc);
  k_down<<<dim3(16, 6, 2), 256, 0, stream>>>(dwn, dwb, xcbuf, xd);
  k_xdblc<<<60, 256, 0, stream>>>(xd, xpcw, xdbl_c);
  k_dtc<<<192, 256, 0, stream>>>(xdbl_c, dtcw, dtcb, dt_c);
  k_scan_ch<<<dim3(8, 2), 256, 0, stream>>>(xdbl_c, dt_c, xd, Alc, Dsc, y_ch);
  k_up<<<dim3(32, 3, 2), 256, 0, stream>>>(upw, upb, y_ch, y_acc);
  k_lngate<<<1024, 256, 0, stream>>>(y_acc, zbuf, nw, nb, tbuf);
  k_outproj<<<dim3(64, 2), 256, 0, stream>>>(tbuf, opw, out);
}

// Round 12
// 385.659 us; speedup vs baseline: 1.0362x; 1.0362x over previous
//
#include <hip/hip_runtime.h>
#include <hip/hip_fp16.h>
#include <cstddef>

// SS3D block: in_proj -> dwconv3d+silu -> {12-dir spatial selective scan + channel selective scan}
// -> layernorm -> *silu(z) -> out_proj.
// Dims: B=2, H=16, W=16, D=8, L=2048, D_MODEL=96, D_INNER=192, N=16, K=12, R=6,
//       D_PROJ=128, R_CH=8.
// NOTE: the reference's un-permute for directions 3 and 4 is NOT the inverse of the
// forward permutation (VMamba quirk) — output-side shift tables g_h* replicate it exactly.
// Spatial scan: chunked 2-pass parallel linear recurrence.
// History: R2 monolithic 12% occ; R4 scattered loads; R6 xdbl K-split; R8 2 states/lane;
// R9 NCHUNK16+sSO; R10 4 states/lane NCHUNK32 -> 390us, sp2 80us @ 89% VALUBusy.
// R11 (2-step DS batching, 8-way xdbl, pre-sdt) REGRESSED -> reverted to R10 scan code.
// R12: fuse LN+gate into out_proj (quad-DPP row stats, kills k_lngate + tbuf traffic);
// fold y_acc/xd zeroing into k_conv (kills memset dispatch). Scan kernels untouched.

#define NCHUNK 32
#define CLEN   64
#define TSTEP  32
#define NTILE  (CLEN / TSTEP)
#define SCAN_IDX_N 73728   // B*K*C*N = 2*12*192*16

__device__ __forceinline__ float siluf(float v) { return v / (1.0f + __expf(-v)); }
__device__ __forceinline__ float softplusf(float v) {
  return (v > 20.0f) ? v : log1pf(__expf(v));
}

// DPP cross-lane adds (VALU pipe, no LDS latency).
template <int CTRL>
__device__ __forceinline__ float dpp_mov(float v) {
  return __int_as_float(__builtin_amdgcn_update_dpp(0, __float_as_int(v), CTRL, 0xF, 0xF, true));
}
__device__ __forceinline__ float red4_dpp(float v) {  // sum within lane quad
  v += dpp_mov<0xB1>(v);    // quad_perm xor1
  v += dpp_mov<0x4E>(v);    // quad_perm xor2
  return v;
}
__device__ __forceinline__ float red16_dpp(float v) {
  v += dpp_mov<0xB1>(v);
  v += dpp_mov<0x4E>(v);
  v += dpp_mov<0x141>(v);   // row_half_mirror
  v += dpp_mov<0x140>(v);   // row_mirror
  return v;
}

// ---------------------------------------------------------------------------
// K1: in_proj GEMM.  out[i,j] = sum_k x[i,k]*W[j,k], i in [0,4096), j in [0,384).
__global__ __launch_bounds__(256) void k_inproj(const float* __restrict__ x,
    const float* __restrict__ W, float* __restrict__ xin_t, float* __restrict__ z) {
  __shared__ float As[64][17];
  __shared__ float Bs[64][17];
  int i0 = blockIdx.x * 64, j0 = blockIdx.y * 64;
  int tid = threadIdx.x, tx = tid & 15, ty = tid >> 4;
  int lrow = tid >> 2, lk4 = (tid & 3) << 2;
  float acc[4][4] = {};
  for (int k0 = 0; k0 < 96; k0 += 16) {
    float4 va = *(const float4*)(x + (size_t)(i0 + lrow) * 96 + k0 + lk4);
    float4 vb = *(const float4*)(W + (size_t)(j0 + lrow) * 96 + k0 + lk4);
    As[lrow][lk4+0] = va.x; As[lrow][lk4+1] = va.y; As[lrow][lk4+2] = va.z; As[lrow][lk4+3] = va.w;
    Bs[lrow][lk4+0] = vb.x; Bs[lrow][lk4+1] = vb.y; Bs[lrow][lk4+2] = vb.z; Bs[lrow][lk4+3] = vb.w;
    __syncthreads();
#pragma unroll
    for (int kk = 0; kk < 16; ++kk) {
      float a0 = As[ty*4+0][kk], a1 = As[ty*4+1][kk], a2 = As[ty*4+2][kk], a3 = As[ty*4+3][kk];
      float b0 = Bs[tx*4+0][kk], b1 = Bs[tx*4+1][kk], b2 = Bs[tx*4+2][kk], b3 = Bs[tx*4+3][kk];
      acc[0][0] = fmaf(a0,b0,acc[0][0]); acc[0][1] = fmaf(a0,b1,acc[0][1]);
      acc[0][2] = fmaf(a0,b2,acc[0][2]); acc[0][3] = fmaf(a0,b3,acc[0][3]);
      acc[1][0] = fmaf(a1,b0,acc[1][0]); acc[1][1] = fmaf(a1,b1,acc[1][1]);
      acc[1][2] = fmaf(a1,b2,acc[1][2]); acc[1][3] = fmaf(a1,b3,acc[1][3]);
      acc[2][0] = fmaf(a2,b0,acc[2][0]); acc[2][1] = fmaf(a2,b1,acc[2][1]);
      acc[2][2] = fmaf(a2,b2,acc[2][2]); acc[2][3] = fmaf(a2,b3,acc[2][3]);
      acc[3][0] = fmaf(a3,b0,acc[3][0]); acc[3][1] = fmaf(a3,b1,acc[3][1]);
      acc[3][2] = fmaf(a3,b2,acc[3][2]); acc[3][3] = fmaf(a3,b3,acc[3][3]);
    }
    __syncthreads();
  }
#pragma unroll
  for (int r = 0; r < 4; ++r) {
    int i = i0 + ty*4 + r; int b = i >> 11, l = i & 2047;
#pragma unroll
    for (int sc = 0; sc < 4; ++sc) {
      int j = j0 + tx*4 + sc;
      float v = acc[r][sc];
      if (j < 192) xin_t[((size_t)b*192 + j)*2048 + l] = v;
      else         z[((size_t)(b*2048 + l))*192 + (j - 192)] = siluf(v);
    }
  }
}

// ---------------------------------------------------------------------------
// K2: depthwise 3x3x3 conv (SAME, zero pad) + bias + silu. Also zeroes y_acc (1:1
// thread map) and xd (first 49152 threads) — replaces the memset dispatch.
__global__ __launch_bounds__(256) void k_conv(const float* __restrict__ xin_t,
    const float* __restrict__ cw, const float* __restrict__ cb, float* __restrict__ xc,
    float* __restrict__ y_acc, float* __restrict__ xd) {
  int idx = blockIdx.x * 256 + threadIdx.x;       // (b*192+c)*2048 + l
  y_acc[idx] = 0.0f;
  if (idx < 49152) xd[idx] = 0.0f;
  int l = idx & 2047; int bc = idx >> 11; int c = bc % 192;
  int d = l & 7, w = (l >> 3) & 15, h = l >> 7;
  const float* xp = xin_t + (size_t)bc * 2048;
  const float* wp = cw + c * 27;
  float acc = cb[c];
#pragma unroll
  for (int kh = -1; kh <= 1; ++kh) {
    int hh = h + kh; if (hh < 0 || hh > 15) continue;
#pragma unroll
    for (int kw = -1; kw <= 1; ++kw) {
      int ww = w + kw; if (ww < 0 || ww > 15) continue;
#pragma unroll
      for (int kd = -1; kd <= 1; ++kd) {
        int dd = d + kd; if (dd < 0 || dd > 7) continue;
        acc = fmaf(xp[(hh*16 + ww)*8 + dd], wp[(kh+1)*9 + (kw+1)*3 + (kd+1)], acc);
      }
    }
  }
  xc[idx] = siluf(acc);
}

// Forward permutation decode: scan position l -> (i0,i1,i2); input spatial
// s_in = i0<<h0 | i1<<h1 | i2<<h2 (where u is read).
__device__ __constant__ int c_s2[6]  = {3,4,3,4,4,4};   // log2 dim(i2)
__device__ __constant__ int c_s1[6]  = {4,3,4,3,4,4};   // log2 dim(i1)
__device__ __constant__ int c_h0[6]  = {7,7,3,3,0,0};
__device__ __constant__ int c_h1[6]  = {3,0,7,0,7,3};
__device__ __constant__ int c_h2[6]  = {0,3,0,7,3,7};
// Output-side (reference's actual unperm; NOT the inverse for pk=3,4).
__device__ __constant__ int g_h0[6]  = {7,7,3,0,4,0};
__device__ __constant__ int g_h1[6]  = {3,0,7,8,0,3};
__device__ __constant__ int g_h2[6]  = {0,3,0,4,7,7};

// ---------------------------------------------------------------------------
// K3: per (b,k,l): x_dbl[38] = Wk(38x192) . xs_col(192).
// Thread quad splits the 192-sum 4x, quad-DPP reduce. B/C interleaved; dt-rank raw -> dts_raw.
__global__ __launch_bounds__(256) void k_xdbl(const float* __restrict__ xc,
    const float* __restrict__ xpw, float* __restrict__ xdblT, float* __restrict__ dts_raw) {
  int k = blockIdx.y, b = blockIdx.z;
  int tid = threadIdx.x;
  int l = blockIdx.x * 64 + (tid >> 2);
  int slice = tid & 3;
  __shared__ float sW[38*192];
  for (int i = tid; i < 38*192; i += 256) sW[i] = xpw[k*38*192 + i];
  __syncthreads();
  int pk = k % 6;
  int lr = (k < 6) ? l : (2047 - l);
  int s2 = c_s2[pk], s1 = c_s1[pk];
  int i2 = lr & ((1 << s2) - 1);
  int tt = lr >> s2;
  int i1 = tt & ((1 << s1) - 1);
  int i0 = tt >> s1;
  int s = (i0 << c_h0[pk]) | (i1 << c_h1[pk]) | (i2 << c_h2[pk]);
  float acc[38];
#pragma unroll
  for (int cc = 0; cc < 38; ++cc) acc[cc] = 0.0f;
  const float* up = xc + (size_t)b * 192 * 2048 + s;
  for (int ci = 0; ci < 48; ++ci) {
    int c = ci * 4 + slice;
    float u = up[(size_t)c * 2048];
#pragma unroll
    for (int cc = 0; cc < 38; ++cc) acc[cc] = fmaf(sW[cc*192 + c], u, acc[cc]);
  }
#pragma unroll
  for (int cc = 0; cc < 38; ++cc) { acc[cc] += dpp_mov<0xB1>(acc[cc]); acc[cc] += dpp_mov<0x4E>(acc[cc]); }
  int bk = b * 12 + k;
  float4* xo4 = (float4*)(xdblT + ((size_t)bk * 2048 + l) * 32);
  int n = slice * 4;
  xo4[slice*2]     = make_float4(acc[6+n],  acc[22+n],  acc[7+n],  acc[23+n]);
  xo4[slice*2 + 1] = make_float4(acc[8+n],  acc[24+n],  acc[9+n],  acc[25+n]);
  float* dr = dts_raw + ((size_t)bk * 2048 + l) * 8;
  if (slice == 0) *(float2*)dr       = make_float2(acc[0], acc[1]);
  if (slice == 1) *(float2*)(dr + 2) = make_float2(acc[2], acc[3]);
  if (slice == 2) *(float2*)(dr + 4) = make_float2(acc[4], acc[5]);
}

// ---------------------------------------------------------------------------
// LDS-tiled scan kernels (32-step tiles, register-prefetched staging).
// Block covers 64 c's for one (k, b, chunk j); lane = cs*4+q holds n in {4q..4q+3};
// wave covers 16 c's. dt recomputed from dts_raw in staging.

// K4 pass 1: chunk-local scan from h=0: P = prod(dA), h_end.
__global__ __launch_bounds__(256) void k_scan_pre(const float* __restrict__ xdblT,
    const float* __restrict__ dts_raw, const float* __restrict__ xc,
    const float* __restrict__ dtw, const float* __restrict__ dtb,
    const float* __restrict__ A_logs, float* __restrict__ Pbuf, float* __restrict__ hend) {
  __shared__ float sB[TSTEP*16];     // [li][n] B only
  __shared__ float sDU[64*(TSTEP*2+2)];  // [c_loc][li*2] {dt,u}, row stride 66
  __shared__ float sDTW[64*6];
  __shared__ float sDTB[64];
  int cg = blockIdx.x, k = blockIdx.y;
  int b = blockIdx.z >> 5, j = blockIdx.z & 31;
  int tid = threadIdx.x;
  int lane = tid & 63, wid = tid >> 6;
  int q = lane & 3, cs = lane >> 2;
  int n0 = q * 4;
  int c_loc = wid * 16 + cs;
  int c = cg * 64 + c_loc;
  int bk = b * 12 + k;
  for (int i = tid; i < 384; i += 256) sDTW[i] = dtw[k*1152 + cg*384 + i];
  if (tid < 64)  sDTB[tid] = dtb[k*192 + cg*64 + tid];
  float4 Al = *(const float4*)&A_logs[((size_t)(k*192 + c))*16 + n0];
  float A0 = -__expf(Al.x), A1 = -__expf(Al.y), A2 = -__expf(Al.z), A3 = -__expf(Al.w);
  int pk = k % 6;
  int s2 = c_s2[pk], s1 = c_s1[pk];
  int h0s = c_h0[pk], h1s = c_h1[pk], h2s = c_h2[pk];
  int m2 = (1 << s2) - 1, m1 = (1 << s1) - 1;
  bool rev = (k >= 6);
  int l0 = j * CLEN;
  int dl = tid & 31, cq = tid >> 5;            // DU staging: step dl, c-group cq (8 c's)
  const float4* bcg4 = (const float4*)(xdblT + (size_t)bk * 2048 * 32);
  const float*  drg  = dts_raw + ((size_t)bk * 2048) * 8;
  const float*  ug   = xc + ((size_t)b * 192 + cg * 64 + cq * 8) * 2048;
  // prefetch tile 0
  float4 pbc = bcg4[(l0 + (tid >> 3)) * 8 + (tid & 7)];
  float4 pr0 = *(const float4*)(drg + (size_t)(l0 + dl) * 8);
  float2 pr1 = *(const float2*)(drg + (size_t)(l0 + dl) * 8 + 4);
  float pu[8];
  {
    int l = l0 + dl;
    int lr = rev ? (2047 - l) : l;
    int i2 = lr & m2; int tt2 = lr >> s2; int i1 = tt2 & m1; int i0 = tt2 >> s1;
    int s_in = (i0 << h0s) | (i1 << h1s) | (i2 << h2s);
#pragma unroll
    for (int i = 0; i < 8; ++i) pu[i] = ug[s_in + (size_t)i * 2048];
  }
  float h0 = 0.f, h1 = 0.f, h2 = 0.f, h3 = 0.f;
  float P0 = 1.f, P1 = 1.f, P2 = 1.f, P3 = 1.f;
  for (int t = 0; t < NTILE; ++t) {
    __syncthreads();
    {   // B-only tile: thread reads one BC float4 (covers n-pair), writes 2 B's
      int li = tid >> 3, jj = tid & 7;
      *(float2*)&sB[li*16 + jj*2] = make_float2(pbc.x, pbc.z);
    }
#pragma unroll
    for (int i = 0; i < 8; ++i) {
      int cc = cq * 8 + i;
      const float* wr = &sDTW[cc*6];
      float v = sDTB[cc];
      v = fmaf(pr0.x, wr[0], v); v = fmaf(pr0.y, wr[1], v); v = fmaf(pr0.z, wr[2], v);
      v = fmaf(pr0.w, wr[3], v); v = fmaf(pr1.x, wr[4], v); v = fmaf(pr1.y, wr[5], v);
      *(float2*)&sDU[cc*66 + dl*2] = make_float2(softplusf(v), pu[i]);
    }
    __syncthreads();
    if (t < NTILE - 1) {
      int lt = l0 + (t + 1) * TSTEP;
      pbc = bcg4[(lt + (tid >> 3)) * 8 + (tid & 7)];
      pr0 = *(const float4*)(drg + (size_t)(lt + dl) * 8);
      pr1 = *(const float2*)(drg + (size_t)(lt + dl) * 8 + 4);
      int l = lt + dl;
      int lr = rev ? (2047 - l) : l;
      int i2 = lr & m2; int tt2 = lr >> s2; int i1 = tt2 & m1; int i0 = tt2 >> s1;
      int s_in = (i0 << h0s) | (i1 << h1s) | (i2 << h2s);
#pragma unroll
      for (int i = 0; i < 8; ++i) pu[i] = ug[s_in + (size_t)i * 2048];
    }
#pragma unroll 4
    for (int li = 0; li < TSTEP; ++li) {
      float4 b4 = *(const float4*)&sB[li*16 + n0];
      float2 du = *(const float2*)&sDU[c_loc*66 + li*2];
      float dtu = du.x * du.y;
      float dA0 = __expf(du.x * A0);
      float dA1 = __expf(du.x * A1);
      float dA2 = __expf(du.x * A2);
      float dA3 = __expf(du.x * A3);
      P0 *= dA0; P1 *= dA1; P2 *= dA2; P3 *= dA3;
      h0 = fmaf(h0, dA0, dtu * b4.x);
      h1 = fmaf(h1, dA1, dtu * b4.y);
      h2 = fmaf(h2, dA2, dtu * b4.z);
      h3 = fmaf(h3, dA3, dtu * b4.w);
    }
  }
  size_t idx = ((size_t)bk * 192 + c) * 16 + n0;
  *(float4*)&Pbuf[(size_t)j * SCAN_IDX_N + idx] = make_float4(P0, P1, P2, P3);
  *(float4*)&hend[(size_t)j * SCAN_IDX_N + idx] = make_float4(h0, h1, h2, h3);
}

// K4 carry: serial combine over 32 chunks -> H_init per chunk (in-place over Pbuf).
__global__ __launch_bounds__(256) void k_scan_carry(float* __restrict__ Pbuf,
    const float* __restrict__ hend) {
  int idx = blockIdx.x * 256 + threadIdx.x;    // 73728
  float S = 0.0f;
#pragma unroll
  for (int j = 0; j < NCHUNK; ++j) {
    float p = Pbuf[(size_t)j * SCAN_IDX_N + idx];
    float e = hend[(size_t)j * SCAN_IDX_N + idx];
    Pbuf[(size_t)j * SCAN_IDX_N + idx] = S;     // H_init for chunk j
    S = fmaf(S, p, e);
  }
}

// K4 pass 2: re-scan each chunk from H_init; 4-lane DPP reduce; atomic un-permute.
__global__ __launch_bounds__(256) void k_scan_sp2(const float* __restrict__ xdblT,
    const float* __restrict__ dts_raw, const float* __restrict__ xc,
    const float* __restrict__ dtw, const float* __restrict__ dtb,
    const float* __restrict__ A_logs, const float* __restrict__ Dsv,
    const float* __restrict__ Hinit, float* __restrict__ y_acc) {
  __shared__ float sBC[TSTEP*32];    // [li][2n]=B,[2n+1]=C
  __shared__ float sDU[64*(TSTEP*2+2)];
  __shared__ float sDTW[64*6];
  __shared__ float sDTB[64];
  __shared__ int   sSO[TSTEP];       // s_out*192 per li
  int cg = blockIdx.x, k = blockIdx.y;
  int b = blockIdx.z >> 5, j = blockIdx.z & 31;
  int tid = threadIdx.x;
  int lane = tid & 63, wid = tid >> 6;
  int q = lane & 3, cs = lane >> 2;
  int n0 = q * 4;
  int c_loc = wid * 16 + cs;
  int c = cg * 64 + c_loc;
  int bk = b * 12 + k;
  int ch = k * 192 + c;
  for (int i = tid; i < 384; i += 256) sDTW[i] = dtw[k*1152 + cg*384 + i];
  if (tid < 64)  sDTB[tid] = dtb[k*192 + cg*64 + tid];
  float4 Al = *(const float4*)&A_logs[(size_t)ch*16 + n0];
  float A0 = -__expf(Al.x), A1 = -__expf(Al.y), A2 = -__expf(Al.z), A3 = -__expf(Al.w);
  float Dv = Dsv[ch];
  float* ybase = y_acc + (size_t)b * 2048 * 192 + c;
  int pk = k % 6;
  int s2 = c_s2[pk], s1 = c_s1[pk];
  int h0s = c_h0[pk], h1s = c_h1[pk], h2s = c_h2[pk];
  int e0 = g_h0[pk], e1 = g_h1[pk], e2 = g_h2[pk];
  int m2 = (1 << s2) - 1, m1 = (1 << s1) - 1;
  bool rev = (k >= 6);
  int l0 = j * CLEN;
  int dl = tid & 31, cq = tid >> 5;
  const float4* bcg4 = (const float4*)(xdblT + (size_t)bk * 2048 * 32);
  const float*  drg  = dts_raw + ((size_t)bk * 2048) * 8;
  const float*  ug   = xc + ((size_t)b * 192 + cg * 64 + cq * 8) * 2048;
  float4 pbc = bcg4[(l0 + (tid >> 3)) * 8 + (tid & 7)];
  float4 pr0 = *(const float4*)(drg + (size_t)(l0 + dl) * 8);
  float2 pr1 = *(const float2*)(drg + (size_t)(l0 + dl) * 8 + 4);
  float pu[8];
  {
    int l = l0 + dl;
    int lr = rev ? (2047 - l) : l;
    int i2 = lr & m2; int tt2 = lr >> s2; int i1 = tt2 & m1; int i0 = tt2 >> s1;
    int s_in = (i0 << h0s) | (i1 << h1s) | (i2 << h2s);
#pragma unroll
    for (int i = 0; i < 8; ++i) pu[i] = ug[s_in + (size_t)i * 2048];
  }
  float4 hi = *(const float4*)&Hinit[(size_t)j * SCAN_IDX_N + ((size_t)bk * 192 + c) * 16 + n0];
  float h0 = hi.x, h1 = hi.y, h2 = hi.z, h3 = hi.w;
  for (int t = 0; t < NTILE; ++t) {
    __syncthreads();
    ((float4*)sBC)[tid] = pbc;
#pragma unroll
    for (int i = 0; i < 8; ++i) {
      int cc = cq * 8 + i;
      const float* wr = &sDTW[cc*6];
      float v = sDTB[cc];
      v = fmaf(pr0.x, wr[0], v); v = fmaf(pr0.y, wr[1], v); v = fmaf(pr0.z, wr[2], v);
      v = fmaf(pr0.w, wr[3], v); v = fmaf(pr1.x, wr[4], v); v = fmaf(pr1.y, wr[5], v);
      *(float2*)&sDU[cc*66 + dl*2] = make_float2(softplusf(v), pu[i]);
    }
    if (tid < TSTEP) {                        // s_out*192 broadcast table
      int l = l0 + t*TSTEP + tid;
      int lr = rev ? (2047 - l) : l;
      int i2 = lr & m2; int tt2 = lr >> s2; int i1 = tt2 & m1; int i0 = tt2 >> s1;
      sSO[tid] = ((i0 << e0) | (i1 << e1) | (i2 << e2)) * 192;
    }
    __syncthreads();
    if (t < NTILE - 1) {
      int lt = l0 + (t + 1) * TSTEP;
      pbc = bcg4[(lt + (tid >> 3)) * 8 + (tid & 7)];
      pr0 = *(const float4*)(drg + (size_t)(lt + dl) * 8);
      pr1 = *(const float2*)(drg + (size_t)(lt + dl) * 8 + 4);
      int l = lt + dl;
      int lr = rev ? (2047 - l) : l;
      int i2 = lr & m2; int tt2 = lr >> s2; int i1 = tt2 & m1; int i0 = tt2 >> s1;
      int s_in = (i0 << h0s) | (i1 << h1s) | (i2 << h2s);
#pragma unroll
      for (int i = 0; i < 8; ++i) pu[i] = ug[s_in + (size_t)i * 2048];
    }
#pragma unroll 4
    for (int li = 0; li < TSTEP; ++li) {
      float4 bc0 = ((const float4*)sBC)[li*8 + q*2];      // B(4q),C(4q),B(4q+1),C(4q+1)
      float4 bc1 = ((const float4*)sBC)[li*8 + q*2 + 1];  // B(4q+2),C(4q+2),B(4q+3),C(4q+3)
      float2 du = *(const float2*)&sDU[c_loc*66 + li*2];
      float dtu = du.x * du.y;
      float dA0 = __expf(du.x * A0);
      float dA1 = __expf(du.x * A1);
      float dA2 = __expf(du.x * A2);
      float dA3 = __expf(du.x * A3);
      h0 = fmaf(h0, dA0, dtu * bc0.x);
      h1 = fmaf(h1, dA1, dtu * bc0.z);
      h2 = fmaf(h2, dA2, dtu * bc1.x);
      h3 = fmaf(h3, dA3, dtu * bc1.z);
      float yv = h0 * bc0.y;
      yv = fmaf(h1, bc0.w, yv);
      yv = fmaf(h2, bc1.y, yv);
      yv = fmaf(h3, bc1.w, yv);
      yv = red4_dpp(yv);
      if (q == 0) atomicAdd(ybase + sSO[li], yv + Dv * du.y);
    }
  }
}

// ---------------------------------------------------------------------------
// K5a: xd[b][p][c] = sum_l xc[b][c][l]*down_w[p][l] (+down_b[p]), K-split with atomics.
__global__ __launch_bounds__(256) void k_down(const float* __restrict__ dw,
    const float* __restrict__ db, const float* __restrict__ xc, float* __restrict__ xd) {
  __shared__ float As[64][17];
  __shared__ float Bs[64][17];
  int ks = blockIdx.x;                       // 16 K slices of 128
  int py = blockIdx.y / 3, cy = blockIdx.y % 3;
  int b = blockIdx.z;
  int p0 = py * 64, c0 = cy * 64;
  int tid = threadIdx.x, tx = tid & 15, ty = tid >> 4;
  int lrow = tid >> 2, lk4 = (tid & 3) << 2;
  float acc[4][4] = {};
  int kbase = ks * 128;
  for (int k0 = kbase; k0 < kbase + 128; k0 += 16) {
    float4 va = *(const float4*)(dw + (size_t)(p0 + lrow) * 2048 + k0 + lk4);
    float4 vb = *(const float4*)(xc + ((size_t)b*192 + c0 + lrow) * 2048 + k0 + lk4);
    As[lrow][lk4+0] = va.x; As[lrow][lk4+1] = va.y; As[lrow][lk4+2] = va.z; As[lrow][lk4+3] = va.w;
    Bs[lrow][lk4+0] = vb.x; Bs[lrow][lk4+1] = vb.y; Bs[lrow][lk4+2] = vb.z; Bs[lrow][lk4+3] = vb.w;
    __syncthreads();
#pragma unroll
    for (int kk = 0; kk < 16; ++kk) {
      float a0 = As[ty*4+0][kk], a1 = As[ty*4+1][kk], a2 = As[ty*4+2][kk], a3 = As[ty*4+3][kk];
      float b0 = Bs[tx*4+0][kk], b1 = Bs[tx*4+1][kk], b2 = Bs[tx*4+2][kk], b3 = Bs[tx*4+3][kk];
      acc[0][0] = fmaf(a0,b0,acc[0][0]); acc[0][1] = fmaf(a0,b1,acc[0][1]);
      acc[0][2] = fmaf(a0,b2,acc[0][2]); acc[0][3] = fmaf(a0,b3,acc[0][3]);
      acc[1][0] = fmaf(a1,b0,acc[1][0]); acc[1][1] = fmaf(a1,b1,acc[1][1]);
      acc[1][2] = fmaf(a1,b2,acc[1][2]); acc[1][3] = fmaf(a1,b3,acc[1][3]);
      acc[2][0] = fmaf(a2,b0,acc[2][0]); acc[2][1] = fmaf(a2,b1,acc[2][1]);
      acc[2][2] = fmaf(a2,b2,acc[2][2]); acc[2][3] = fmaf(a2,b3,acc[2][3]);
      acc[3][0] = fmaf(a3,b0,acc[3][0]); acc[3][1] = fmaf(a3,b1,acc[3][1]);
      acc[3][2] = fmaf(a3,b2,acc[3][2]); acc[3][3] = fmaf(a3,b3,acc[3][3]);
    }
    __syncthreads();
  }
#pragma unroll
  for (int r = 0; r < 4; ++r) {
    int p = p0 + ty*4 + r;
    float bias = (ks == 0) ? db[p] : 0.0f;
#pragma unroll
    for (int sc = 0; sc < 4; ++sc) {
      int c = c0 + tx*4 + sc;
      atomicAdd(&xd[((size_t)b*128 + p)*192 + c], acc[r][sc] + bias);
    }
  }
}

// K5b1: xdbl_c[b][n][c] = sum_p xd[b][p][c] * xpc_w[n][p]  (4 indep accumulators for MLP)
__global__ __launch_bounds__(256) void k_xdblc(const float* __restrict__ xd,
    const float* __restrict__ xpcw, float* __restrict__ xdblc) {
  int idx = blockIdx.x * 256 + threadIdx.x;   // 2*40*192 = 15360
  int c = idx % 192; int n = (idx / 192) % 40; int b = idx / (192 * 40);
  const float* xb = xd + (size_t)b*128*192 + c;
  const float* wb = xpcw + n*128;
  float a0 = 0.f, a1 = 0.f, a2 = 0.f, a3 = 0.f;
#pragma unroll 4
  for (int p = 0; p < 128; p += 4) {
    a0 = fmaf(xb[(size_t)(p+0)*192], wb[p+0], a0);
    a1 = fmaf(xb[(size_t)(p+1)*192], wb[p+1], a1);
    a2 = fmaf(xb[(size_t)(p+2)*192], wb[p+2], a2);
    a3 = fmaf(xb[(size_t)(p+3)*192], wb[p+3], a3);
  }
  xdblc[((size_t)b*40 + n)*192 + c] = (a0 + a1) + (a2 + a3);
}

// K5b2: dt_c[b][p][c] = softplus(sum_r xdbl_c[b][r][c]*dtc_w[p][r] + dtc_b[p])
__global__ __launch_bounds__(256) void k_dtc(const float* __restrict__ xdblc,
    const float* __restrict__ dtcw, const float* __restrict__ dtcb, float* __restrict__ dt_c) {
  int idx = blockIdx.x * 256 + threadIdx.x;   // 2*128*192 = 49152
  int c = idx % 192; int p = (idx / 192) % 128; int b = idx / (192 * 128);
  float acc = dtcb[p];
#pragma unroll
  for (int r = 0; r < 8; ++r)
    acc = fmaf(xdblc[((size_t)b*40 + r)*192 + c], dtcw[p*8 + r], acc);
  dt_c[idx] = softplusf(acc);
}

// K5c: channel selective scan over 192 steps; lane per (p,n); float4 batch prefetch (MLP).
__global__ __launch_bounds__(256) void k_scan_ch(const float* __restrict__ xdblc,
    const float* __restrict__ dt_c, const float* __restrict__ xd,
    const float* __restrict__ Alc, const float* __restrict__ Dsc, float* __restrict__ y_ch) {
  int pg = blockIdx.x, b = blockIdx.y;
  int lane = threadIdx.x & 63, wid = threadIdx.x >> 6;
  int p = pg * 16 + wid * 4 + (lane >> 4);
  int n = lane & 15;
  float A = -__expf(Alc[p * 16 + n]);
  float Dv = Dsc[p];
  const float* Brow = xdblc + ((size_t)b*40 + 8 + n) * 192;
  const float* Crow = Brow + (size_t)16 * 192;
  const float* dtrow = dt_c + ((size_t)b*128 + p) * 192;
  const float* urow = xd + ((size_t)b*128 + p) * 192;
  float* yrow = y_ch + ((size_t)b*128 + p) * 192;
  float h = 0.0f;
  float4 d4 = *(const float4*)dtrow;
  float4 u4 = *(const float4*)urow;
  float4 B4 = *(const float4*)Brow;
  float4 C4 = *(const float4*)Crow;
  for (int ct0 = 0; ct0 < 192; ct0 += 4) {
    float4 nd, nu, nB, nC;
    if (ct0 < 188) {
      nd = *(const float4*)(dtrow + ct0 + 4);
      nu = *(const float4*)(urow + ct0 + 4);
      nB = *(const float4*)(Brow + ct0 + 4);
      nC = *(const float4*)(Crow + ct0 + 4);
    }
    float dts[4] = {d4.x, d4.y, d4.z, d4.w};
    float us[4]  = {u4.x, u4.y, u4.z, u4.w};
    float Bs_[4] = {B4.x, B4.y, B4.z, B4.w};
    float Cs_[4] = {C4.x, C4.y, C4.z, C4.w};
#pragma unroll
    for (int s = 0; s < 4; ++s) {
      float dA = __expf(dts[s] * A);
      h = fmaf(h, dA, dts[s] * us[s] * Bs_[s]);
      float yv = red16_dpp(h * Cs_[s]);
      if (n == 0) yrow[ct0 + s] = yv + Dv * us[s];
    }
    d4 = nd; u4 = nu; B4 = nB; C4 = nC;
  }
}

// K5d: y_acc[b][l][c] += sum_p y_ch[b][p][c]*up_w[l][p] + up_b[l]
__global__ __launch_bounds__(256) void k_up(const float* __restrict__ uw,
    const float* __restrict__ ub, const float* __restrict__ ych, float* __restrict__ y_acc) {
  __shared__ float As[64][17];
  __shared__ float Bs[64][17];
  int l0 = blockIdx.x * 64, c0 = blockIdx.y * 64, b = blockIdx.z;
  int tid = threadIdx.x, tx = tid & 15, ty = tid >> 4;
  int lrow = tid >> 2, lk4 = (tid & 3) << 2;
  int bc4 = (tid & 15) << 2, bpp = tid >> 4;    // B-tile loader: 4 consecutive c at fixed p
  float acc[4][4] = {};
  for (int k0 = 0; k0 < 128; k0 += 16) {
    float4 va = *(const float4*)(uw + (size_t)(l0 + lrow) * 128 + k0 + lk4);
    float4 vb = *(const float4*)(ych + ((size_t)b*128 + k0 + bpp) * 192 + c0 + bc4);
    As[lrow][lk4+0] = va.x; As[lrow][lk4+1] = va.y; As[lrow][lk4+2] = va.z; As[lrow][lk4+3] = va.w;
    Bs[bc4+0][bpp] = vb.x; Bs[bc4+1][bpp] = vb.y; Bs[bc4+2][bpp] = vb.z; Bs[bc4+3][bpp] = vb.w;
    __syncthreads();
#pragma unroll
    for (int kk = 0; kk < 16; ++kk) {
      float a0 = As[ty*4+0][kk], a1 = As[ty*4+1][kk], a2 = As[ty*4+2][kk], a3 = As[ty*4+3][kk];
      float b0 = Bs[tx*4+0][kk], b1 = Bs[tx*4+1][kk], b2 = Bs[tx*4+2][kk], b3 = Bs[tx*4+3][kk];
      acc[0][0] = fmaf(a0,b0,acc[0][0]); acc[0][1] = fmaf(a0,b1,acc[0][1]);
      acc[0][2] = fmaf(a0,b2,acc[0][2]); acc[0][3] = fmaf(a0,b3,acc[0][3]);
      acc[1][0] = fmaf(a1,b0,acc[1][0]); acc[1][1] = fmaf(a1,b1,acc[1][1]);
      acc[1][2] = fmaf(a1,b2,acc[1][2]); acc[1][3] = fmaf(a1,b3,acc[1][3]);
      acc[2][0] = fmaf(a2,b0,acc[2][0]); acc[2][1] = fmaf(a2,b1,acc[2][1]);
      acc[2][2] = fmaf(a2,b2,acc[2][2]); acc[2][3] = fmaf(a2,b3,acc[2][3]);
      acc[3][0] = fmaf(a3,b0,acc[3][0]); acc[3][1] = fmaf(a3,b1,acc[3][1]);
      acc[3][2] = fmaf(a3,b2,acc[3][2]); acc[3][3] = fmaf(a3,b3,acc[3][3]);
    }
    __syncthreads();
  }
#pragma unroll
  for (int r = 0; r < 4; ++r) {
    int l = l0 + ty*4 + r;
    float ubl = ub[l];
#pragma unroll
    for (int sc = 0; sc < 4; ++sc) {
      int c = c0 + tx*4 + sc;
      size_t idx = ((size_t)b*2048 + l) * 192 + c;
      y_acc[idx] += acc[r][sc] + ubl;
    }
  }
}

// K6: fused layernorm(192) + silu(z) gate + out_proj GEMM.
// Row stats via quad-DPP butterfly (each thread quad owns one row; all lanes end
// with the full sums, so mu/rstd live in registers — no extra syncs).
__global__ __launch_bounds__(256) void k_lnoutproj(const float* __restrict__ y_acc,
    const float* __restrict__ z, const float* __restrict__ nw, const float* __restrict__ nb,
    const float* __restrict__ W, float* __restrict__ out) {
  __shared__ float As[64][17];
  __shared__ float Bs[64][17];
  __shared__ float sNW[192], sNB[192];
  int i0 = blockIdx.x * 64, j0 = blockIdx.y * 64;
  int tid = threadIdx.x, tx = tid & 15, ty = tid >> 4;
  int lrow = tid >> 2, lk4 = (tid & 3) << 2;
  if (tid < 192) { sNW[tid] = nw[tid]; sNB[tid] = nb[tid]; }
  // row stats for row i0+lrow (quad q = tid&3 sums cols q*48..q*48+47)
  float mu, rstd;
  {
    int qq = tid & 3;
    const float* yr = y_acc + (size_t)(i0 + lrow) * 192 + qq * 48;
    float s = 0.f, ss = 0.f;
    for (int e = 0; e < 48; e += 4) {
      float4 v = *(const float4*)(yr + e);
      s += (v.x + v.y) + (v.z + v.w);
      ss = fmaf(v.x, v.x, fmaf(v.y, v.y, fmaf(v.z, v.z, fmaf(v.w, v.w, ss))));
    }
    s = red4_dpp(s); ss = red4_dpp(ss);
    mu = s * (1.0f / 192.0f);
    float var = ss * (1.0f / 192.0f) - mu * mu;
    rstd = rsqrtf(var + 1e-5f);
  }
  __syncthreads();   // sNW/sNB visible
  float acc[4][4] = {};
  for (int k0 = 0; k0 < 192; k0 += 16) {
    float4 vy = *(const float4*)(y_acc + (size_t)(i0 + lrow) * 192 + k0 + lk4);
    float4 vz = *(const float4*)(z + (size_t)(i0 + lrow) * 192 + k0 + lk4);
    int wr = j0 + lrow;
    float4 vb = (wr < 96) ? *(const float4*)(W + (size_t)wr * 192 + k0 + lk4)
                          : make_float4(0.f, 0.f, 0.f, 0.f);
    As[lrow][lk4+0] = fmaf((vy.x - mu) * rstd, sNW[k0+lk4+0], sNB[k0+lk4+0]) * vz.x;
    As[lrow][lk4+1] = fmaf((vy.y - mu) * rstd, sNW[k0+lk4+1], sNB[k0+lk4+1]) * vz.y;
    As[lrow][lk4+2] = fmaf((vy.z - mu) * rstd, sNW[k0+lk4+2], sNB[k0+lk4+2]) * vz.z;
    As[lrow][lk4+3] = fmaf((vy.w - mu) * rstd, sNW[k0+lk4+3], sNB[k0+lk4+3]) * vz.w;
    Bs[lrow][lk4+0] = vb.x; Bs[lrow][lk4+1] = vb.y; Bs[lrow][lk4+2] = vb.z; Bs[lrow][lk4+3] = vb.w;
    __syncthreads();
#pragma unroll
    for (int kk = 0; kk < 16; ++kk) {
      float a0 = As[ty*4+0][kk], a1 = As[ty*4+1][kk], a2 = As[ty*4+2][kk], a3 = As[ty*4+3][kk];
      float b0 = Bs[tx*4+0][kk], b1 = Bs[tx*4+1][kk], b2 = Bs[tx*4+2][kk], b3 = Bs[tx*4+3][kk];
      acc[0][0] = fmaf(a0,b0,acc[0][0]); acc[0][1] = fmaf(a0,b1,acc[0][1]);
      acc[0][2] = fmaf(a0,b2,acc[0][2]); acc[0][3] = fmaf(a0,b3,acc[0][3]);
      acc[1][0] = fmaf(a1,b0,acc[1][0]); acc[1][1] = fmaf(a1,b1,acc[1][1]);
      acc[1][2] = fmaf(a1,b2,acc[1][2]); acc[1][3] = fmaf(a1,b3,acc[1][3]);
      acc[2][0] = fmaf(a2,b0,acc[2][0]); acc[2][1] = fmaf(a2,b1,acc[2][1]);
      acc[2][2] = fmaf(a2,b2,acc[2][2]); acc[2][3] = fmaf(a2,b3,acc[2][3]);
      acc[3][0] = fmaf(a3,b0,acc[3][0]); acc[3][1] = fmaf(a3,b1,acc[3][1]);
      acc[3][2] = fmaf(a3,b2,acc[3][2]); acc[3][3] = fmaf(a3,b3,acc[3][3]);
    }
    __syncthreads();
  }
#pragma unroll
  for (int r = 0; r < 4; ++r) {
    int i = i0 + ty*4 + r;
#pragma unroll
    for (int sc = 0; sc < 4; ++sc) {
      int j = j0 + tx*4 + sc;
      if (j < 96) out[(size_t)i * 96 + j] = acc[r][sc];
    }
  }
}

// ---------------------------------------------------------------------------
extern "C" void kernel_launch(void* const* d_in, const int* in_sizes, int n_in,
                              void* d_out, int out_size, void* d_ws, size_t ws_size,
                              hipStream_t stream) {
  (void)in_sizes; (void)n_in; (void)out_size; (void)ws_size;
  const float* x    = (const float*)d_in[0];
  const float* ipw  = (const float*)d_in[1];
  const float* cw   = (const float*)d_in[2];
  const float* cb   = (const float*)d_in[3];
  const float* xpw  = (const float*)d_in[4];
  const float* dtw  = (const float*)d_in[5];
  const float* dtb  = (const float*)d_in[6];
  const float* Alog = (const float*)d_in[7];
  const float* Dsp  = (const float*)d_in[8];
  const float* xpcw = (const float*)d_in[9];
  const float* dtcw = (const float*)d_in[10];
  const float* dtcb = (const float*)d_in[11];
  const float* Alc  = (const float*)d_in[12];
  const float* Dsc  = (const float*)d_in[13];
  const float* dwn  = (const float*)d_in[14];
  const float* dwb  = (const float*)d_in[15];
  const float* upw  = (const float*)d_in[16];
  const float* upb  = (const float*)d_in[17];
  const float* nw   = (const float*)d_in[18];
  const float* nb   = (const float*)d_in[19];
  const float* opw  = (const float*)d_in[20];
  float* out = (float*)d_out;

  float* ws = (float*)d_ws;
  float* xin_t  = ws;                         // 786432  (B,192,L); dead after conv
  float* zbuf   = xin_t + 786432;             // 786432  (B,L,192) silu'd
  float* xcbuf  = zbuf + 786432;              // 786432  (B,192,L)
  float* xdblT  = xcbuf + 786432;             // 1572864 (B,12,L,32) interleaved B/C
  float* dts_r  = xdblT + 1572864;            // 393216  (B,12,L,8) raw dt-rank values
  float* y_acc  = dts_r + 393216;             // 786432  (B,L,192)  [zeroed by k_conv]
  float* xd     = y_acc + 786432;             // 49152   (B,128,192) [zeroed by k_conv]
  float* xdbl_c = xd + 49152;                 // 15360   (B,40,192)
  float* dt_c   = xdbl_c + 15360;             // 49152   (B,128,192)
  float* y_ch   = dt_c + 49152;               // 49152   (B,128,192)
  float* Pbuf   = y_ch + 49152;               // NCHUNK*73728 = 2359296
  float* hendb  = Pbuf + 2359296;             // 2359296   (total ~37 MB)

  k_inproj<<<dim3(64, 6), 256, 0, stream>>>(x, ipw, xin_t, zbuf);
  k_conv<<<3072, 256, 0, stream>>>(xin_t, cw, cb, xcbuf, y_acc, xd);
  k_xdbl<<<dim3(32, 12, 2), 256, 0, stream>>>(xcbuf, xpw, xdblT, dts_r);
  k_scan_pre<<<dim3(3, 12, 64), 256, 0, stream>>>(xdblT, dts_r, xcbuf, dtw, dtb, Alog, Pbuf, hendb);
  k_scan_carry<<<288, 256, 0, stream>>>(Pbuf, hendb);
  k_scan_sp2<<<dim3(3, 12, 64), 256, 0, stream>>>(xdblT, dts_r, xcbuf, dtw, dtb, Alog, Dsp, Pbuf, y_acc);
  k_down<<<dim3(16, 6, 2), 256, 0, stream>>>(dwn, dwb, xcbuf, xd);
  k_xdblc<<<60, 256, 0, stream>>>(xd, xpcw, xdbl_c);
  k_dtc<<<192, 256, 0, stream>>>(xdbl_c, dtcw, dtcb, dt_c);
  k_scan_ch<<<dim3(8, 2), 256, 0, stream>>>(xdbl_c, dt_c, xd, Alc, Dsc, y_ch);
  k_up<<<dim3(32, 3, 2), 256, 0, stream>>>(upw, upb, y_ch, y_acc);
  k_lnoutproj<<<dim3(64, 2), 256, 0, stream>>>(y_acc, zbuf, nw, nb, opw, out);
}